// Round 5
// baseline (181.878 us; speedup 1.0000x reference)
//
#include <hip/hip_runtime.h>
#include <math.h>

#define ALPHA 0.2f

typedef float f32x4 __attribute__((ext_vector_type(4)));
typedef __bf16 bf16x8 __attribute__((ext_vector_type(8)));
typedef unsigned short u16x8 __attribute__((ext_vector_type(8)));

__device__ __forceinline__ unsigned short f2bf(float f) {
    union { float f; unsigned int u; } v; v.f = f;
    unsigned int u = v.u;
    return (unsigned short)((u + 0x7fffu + ((u >> 16) & 1u)) >> 16);  // RNE
}
__device__ __forceinline__ float bf_lo(unsigned int d) {
    union { unsigned int u; float f; } v; v.u = d << 16; return v.f;
}
__device__ __forceinline__ float bf_hi(unsigned int d) {
    union { unsigned int u; float f; } v; v.u = d & 0xffff0000u; return v.f;
}
__device__ __forceinline__ float sigmoidf_(float v) {
    return 1.f / (1.f + __expf(-v));
}

// ---------------------------------------------------------------------------
// Kernel 0: convert/pack.
//  blocks [0,128):   xT_bf[b][k][w] = bf16(x[b][w][k])       (8,256,256)
//  blocks [128,256): Wb[e2][w] = bf16(e2<512 ? W[e2][w] : W[e2-512][256+w])
//  block  256:       c2g[e] = 0.4*a[e]
// ---------------------------------------------------------------------------
__global__ __launch_bounds__(256) void convert_kernel(
    const float* __restrict__ x, const float* __restrict__ W,
    const float* __restrict__ a,
    unsigned short* __restrict__ xT, unsigned short* __restrict__ Wb,
    float* __restrict__ c2g)
{
    const int tid = threadIdx.x;
    if (blockIdx.x < 128) {
        const int b  = blockIdx.x >> 4;
        const int tt = blockIdx.x & 15;
        const int k0 = (tt >> 2) * 64;
        const int w0 = (tt & 3) * 64;
        __shared__ float Td[64][68];   // Td[k][w]
        const int wl = tid >> 4;       // 0..15
        const int kg = tid & 15;       // 0..15
        #pragma unroll
        for (int p = 0; p < 4; p++) {
            const int w = wl + 16 * p;
            const float4 v = *(const float4*)(x + b * 65536 + (w0 + w) * 256 + k0 + kg * 4);
            Td[kg * 4 + 0][w] = v.x;
            Td[kg * 4 + 1][w] = v.y;
            Td[kg * 4 + 2][w] = v.z;
            Td[kg * 4 + 3][w] = v.w;
        }
        __syncthreads();
        const int c8 = (tid & 7) * 8;
        #pragma unroll
        for (int p = 0; p < 2; p++) {
            const int rk = (tid >> 3) + 32 * p;
            u16x8 o;
            #pragma unroll
            for (int j = 0; j < 8; j++) o[j] = f2bf(Td[rk][c8 + j]);
            *(u16x8*)(xT + b * 65536 + (k0 + rk) * 256 + w0 + c8) = o;
        }
    } else if (blockIdx.x < 256) {
        const int base = (blockIdx.x - 128) * 2048 + tid * 8;
        const int e2 = base >> 8;
        const int w8 = base & 255;
        const float* src = (e2 < 512) ? (W + e2 * 512 + w8)
                                      : (W + (e2 - 512) * 512 + 256 + w8);
        const float4 v0 = *(const float4*)(src);
        const float4 v1 = *(const float4*)(src + 4);
        u16x8 o;
        o[0] = f2bf(v0.x); o[1] = f2bf(v0.y); o[2] = f2bf(v0.z); o[3] = f2bf(v0.w);
        o[4] = f2bf(v1.x); o[5] = f2bf(v1.y); o[6] = f2bf(v1.z); o[7] = f2bf(v1.w);
        *(u16x8*)(Wb + e2 * 256 + w8) = o;
    } else {
        c2g[tid]       = 0.4f * a[tid];
        c2g[tid + 256] = 0.4f * a[tid + 256];
    }
}

// ---------------------------------------------------------------------------
// Kernel 1: MFMA bf16 GEMM, C[m][n] = sum_k A[m][k]*B[n][k], K=256.
//  left  (tiles 0..31):  A=xT[b], B=Wb[0:512]  -> Lp[b][k][e] = C + b_lin[e]
//  right (tiles 32..63): A=Wb[512:], B=xT[b]   ->
//        R2[b][e>>3][j][e&7] = bf16(C)  (8 e-values packed per 16B per j)
//        rg[b][j] += 1.5 * sum_e c2[e]*C[e][j]   (rank-1 softmax term, atomics)
// ---------------------------------------------------------------------------
__global__ __launch_bounds__(256) void mfma_gemm_kernel(
    const unsigned short* __restrict__ xT, const unsigned short* __restrict__ Wb,
    const float* __restrict__ b_lin, const float* __restrict__ c2g,
    float* __restrict__ Lp, unsigned short* __restrict__ R2,
    float* __restrict__ rg)
{
    const int b = blockIdx.y;
    const int t = blockIdx.x;
    const bool left = (t < 32);
    const unsigned short *A, *B;
    int m0, n0;
    if (left) {
        m0 = (t >> 3) * 64; n0 = (t & 7) * 64;
        A = xT + b * 65536; B = Wb;
    } else {
        const int tt = t - 32;
        m0 = (tt >> 2) * 64; n0 = (tt & 3) * 64;
        A = Wb + 512 * 256; B = xT + b * 65536;
    }

    __shared__ unsigned short As[64][72];
    __shared__ unsigned short Bs[64][72];

    const int tid  = threadIdx.x;
    const int wv   = tid >> 6;
    const int lane = tid & 63;
    const int wy = wv >> 1, wx = wv & 1;
    const int lr = lane & 15;
    const int lk = lane >> 4;

    f32x4 acc[2][2];
    #pragma unroll
    for (int i = 0; i < 2; i++)
        #pragma unroll
        for (int j = 0; j < 2; j++) acc[i][j] = (f32x4){0.f, 0.f, 0.f, 0.f};

    const int sr = tid >> 3;           // 0..31
    const int sc = (tid & 7) * 8;      // 0..56

    for (int k0 = 0; k0 < 256; k0 += 64) {
        *(u16x8*)&As[sr][sc]      = *(const u16x8*)(A + (m0 + sr) * 256 + k0 + sc);
        *(u16x8*)&As[sr + 32][sc] = *(const u16x8*)(A + (m0 + sr + 32) * 256 + k0 + sc);
        *(u16x8*)&Bs[sr][sc]      = *(const u16x8*)(B + (n0 + sr) * 256 + k0 + sc);
        *(u16x8*)&Bs[sr + 32][sc] = *(const u16x8*)(B + (n0 + sr + 32) * 256 + k0 + sc);
        __syncthreads();
        #pragma unroll
        for (int kk = 0; kk < 64; kk += 32) {
            const bf16x8 a0 = *(const bf16x8*)&As[wy * 32 + lr][kk + lk * 8];
            const bf16x8 a1 = *(const bf16x8*)&As[wy * 32 + 16 + lr][kk + lk * 8];
            const bf16x8 b0 = *(const bf16x8*)&Bs[wx * 32 + lr][kk + lk * 8];
            const bf16x8 b1 = *(const bf16x8*)&Bs[wx * 32 + 16 + lr][kk + lk * 8];
            acc[0][0] = __builtin_amdgcn_mfma_f32_16x16x32_bf16(a0, b0, acc[0][0], 0, 0, 0);
            acc[0][1] = __builtin_amdgcn_mfma_f32_16x16x32_bf16(a0, b1, acc[0][1], 0, 0, 0);
            acc[1][0] = __builtin_amdgcn_mfma_f32_16x16x32_bf16(a1, b0, acc[1][0], 0, 0, 0);
            acc[1][1] = __builtin_amdgcn_mfma_f32_16x16x32_bf16(a1, b1, acc[1][1], 0, 0, 0);
        }
        __syncthreads();
    }

    // C/D layout: col = lane&15, row = (lane>>4)*4 + reg
    if (left) {
        #pragma unroll
        for (int mi = 0; mi < 2; mi++) {
            #pragma unroll
            for (int ni = 0; ni < 2; ni++) {
                const int row = m0 + wy * 32 + mi * 16 + lk * 4;
                const int col = n0 + wx * 32 + ni * 16 + lr;
                #pragma unroll
                for (int r = 0; r < 4; r++)
                    Lp[b * 131072 + (row + r) * 512 + col] = acc[mi][ni][r] + b_lin[col];
            }
        }
    } else {
        unsigned short* R2b = R2 + b * 131072;   // 512e x 256j per batch
        #pragma unroll
        for (int mi = 0; mi < 2; mi++) {
            #pragma unroll
            for (int ni = 0; ni < 2; ni++) {
                const int row = m0 + wy * 32 + mi * 16 + lk * 4;   // e base (4 vals)
                const int col = n0 + wx * 32 + ni * 16 + lr;       // j
                ushort4 o;
                o.x = f2bf(acc[mi][ni][0]);
                o.y = f2bf(acc[mi][ni][1]);
                o.z = f2bf(acc[mi][ni][2]);
                o.w = f2bf(acc[mi][ni][3]);
                *(ushort4*)(R2b + (row >> 3) * 2048 + col * 8 + (row & 7)) = o;
            }
        }
        // rank-1 term: rg[b][j] += 1.5 * sum_e c2[e] * R[e][j]
        #pragma unroll
        for (int ni = 0; ni < 2; ni++) {
            const int col = n0 + wx * 32 + ni * 16 + lr;
            float rv = 0.f;
            #pragma unroll
            for (int mi = 0; mi < 2; mi++) {
                const int row = m0 + wy * 32 + mi * 16 + lk * 4;
                const float4 cc = *(const float4*)(c2g + row);
                rv += cc.x * acc[mi][ni][0] + cc.y * acc[mi][ni][1]
                    + cc.z * acc[mi][ni][2] + cc.w * acc[mi][ni][3];
            }
            rv += __shfl_xor(rv, 16);
            rv += __shfl_xor(rv, 32);
            if (lk == 0) atomicAdd(rg + b * 256 + col, 1.5f * rv);
        }
    }
}

// ---------------------------------------------------------------------------
// Kernel 2: score + softmax + attn@v + sigmoid + T-store.
// 1024 threads = (j 0..255) x (e-quarter 0..3); grid 512 = (b, i-tile of 4).
// Hot loop reads L rows + c2 via wave-uniform (scalar) loads, R via uint4.
// score[i][j] = u15[i] + rg[j] + sum_e c2[e]*|L[i,e]+R[e,j]| + bias[i][j]
// ---------------------------------------------------------------------------
__global__ __launch_bounds__(1024, 8) void attn_kernel(
    const float* __restrict__ x,              // (8,256,256)
    const float* __restrict__ Lp,             // (8,256,512) fp32, b_lin folded
    const unsigned int* __restrict__ R2u,     // (8,64,256,4) dwords (bf16 pairs)
    const float* __restrict__ c2g,            // (512) = 0.4*a
    const float* __restrict__ rg,             // (8,256) rank-1 right term (x1.5)
    const float* __restrict__ bias,           // (256,256)
    float* __restrict__ out)                  // (8,256,256)
{
    const int b   = blockIdx.x >> 6;
    const int i0  = (blockIdx.x & 63) * 4;
    const int tid = threadIdx.x;
    const int j   = tid & 255;
    const int q   = __builtin_amdgcn_readfirstlane(tid >> 8);  // wave-uniform quarter

    __shared__ float buf[5124];
    float* acc2P = buf;            // [4 q][4 i][256 j]  (reused as hp later)
    float* at    = buf + 4096;     // [4][256]
    float* u_s15 = buf + 5120;     // [4]

    // ---- u15[i] = 1.5 * sum_e c2[e]*L[i,e], by waves 0..3 (no sync needed yet)
    if (tid < 256) {
        const int i = tid >> 6, lane = tid & 63;
        const float* Lr = Lp + b * 131072 + (i0 + i) * 512 + lane * 8;
        const float* cr = c2g + lane * 8;
        const float4 la = *(const float4*)Lr;
        const float4 lb = *(const float4*)(Lr + 4);
        const float4 ca = *(const float4*)cr;
        const float4 cb = *(const float4*)(cr + 4);
        float p = la.x * ca.x + la.y * ca.y + la.z * ca.z + la.w * ca.w
                + lb.x * cb.x + lb.y * cb.y + lb.z * cb.z + lb.w * cb.w;
        #pragma unroll
        for (int off = 32; off; off >>= 1) p += __shfl_xor(p, off);
        if (lane == 0) u_s15[i] = 1.5f * p;
    }

    // ---- score phase: 128 e per thread; L/c2 via scalar loads, R via uint4
    const float* Lq = Lp + b * 131072 + i0 * 512 + q * 128;   // rows stride 512
    const float* cq = c2g + q * 128;
    const unsigned int* Rq = R2u + b * 65536 + q * 16384 + j * 4;

    float acc0 = 0.f, acc1 = 0.f, acc2 = 0.f, acc3 = 0.f;
    #pragma unroll 4
    for (int eo = 0; eo < 128; eo += 8) {
        const uint4 rw = *(const uint4*)(Rq + (eo >> 3) * 1024);
        float r[8];
        r[0] = bf_lo(rw.x); r[1] = bf_hi(rw.x);
        r[2] = bf_lo(rw.y); r[3] = bf_hi(rw.y);
        r[4] = bf_lo(rw.z); r[5] = bf_hi(rw.z);
        r[6] = bf_lo(rw.w); r[7] = bf_hi(rw.w);
        #pragma unroll
        for (int s = 0; s < 8; s++) {
            const float c  = cq[eo + s];
            const float l0 = Lq[eo + s];
            const float l1 = Lq[512 + eo + s];
            const float l2 = Lq[1024 + eo + s];
            const float l3 = Lq[1536 + eo + s];
            acc0 = fmaf(c, fabsf(l0 + r[s]), acc0);
            acc1 = fmaf(c, fabsf(l1 + r[s]), acc1);
            acc2 = fmaf(c, fabsf(l2 + r[s]), acc2);
            acc3 = fmaf(c, fabsf(l3 + r[s]), acc3);
        }
    }
    {
        float* dst = acc2P + q * 1024 + j;
        dst[0]   = acc0;
        dst[256] = acc1;
        dst[512] = acc2;
        dst[768] = acc3;
    }
    __syncthreads();

    // ---- combine: at[i][j] = u15[i] + rg[j] + sum_q acc2P + bias
    if (tid < 256) {
        const float rj = rg[b * 256 + j];
        #pragma unroll
        for (int i = 0; i < 4; i++) {
            float s = u_s15[i] + rj + bias[(i0 + i) * 256 + j];
            #pragma unroll
            for (int qq = 0; qq < 4; qq++) s += acc2P[qq * 1024 + i * 256 + j];
            at[i * 256 + j] = s;
        }
    }
    __syncthreads();

    // ---- softmax: wave i (tid<256) handles row i
    if (tid < 256) {
        const int i = tid >> 6, lane = tid & 63;
        float v[4];
        float m = -1e30f;
        #pragma unroll
        for (int u = 0; u < 4; u++) {
            v[u] = at[i * 256 + lane + 64 * u];
            m = fmaxf(m, v[u]);
        }
        #pragma unroll
        for (int off = 32; off; off >>= 1) m = fmaxf(m, __shfl_xor(m, off));
        float s = 0.f;
        #pragma unroll
        for (int u = 0; u < 4; u++) { v[u] = __expf(v[u] - m); s += v[u]; }
        #pragma unroll
        for (int off = 32; off; off >>= 1) s += __shfl_xor(s, off);
        const float inv = 1.f / s;
        #pragma unroll
        for (int u = 0; u < 4; u++) at[i * 256 + lane + 64 * u] = v[u] * inv;
    }
    __syncthreads();

    // ---- matvec: thread=(w', j-quarter); h[i] = sum_j at[i][j]*x[b][w'][j]
    const int wp = tid & 255;
    const int jq = tid >> 8;
    const float* xrow = x + b * 65536 + wp * 256 + jq * 64;
    float h[4] = {0.f, 0.f, 0.f, 0.f};
    #pragma unroll 4
    for (int jj = 0; jj < 64; jj += 4) {
        const float4 xv = *(const float4*)(xrow + jj);
        const int jg = jq * 64 + jj;
        #pragma unroll
        for (int i = 0; i < 4; i++) {
            const float4 av = *(const float4*)&at[i * 256 + jg];
            h[i] += av.x * xv.x + av.y * xv.y + av.z * xv.z + av.w * xv.w;
        }
    }
    float* hp = buf;               // reuse acc2P region: [4 jq][4 i][256 wp]
    {
        float* dst = hp + jq * 1024 + wp;
        dst[0]   = h[0];
        dst[256] = h[1];
        dst[512] = h[2];
        dst[768] = h[3];
    }
    __syncthreads();
    if (tid < 256) {
        float4 o;
        #pragma unroll
        for (int i = 0; i < 4; i++) {
            float s = hp[i * 256 + wp] + hp[1024 + i * 256 + wp]
                    + hp[2048 + i * 256 + wp] + hp[3072 + i * 256 + wp];
            ((float*)&o)[i] = sigmoidf_(s);
        }
        *(float4*)(out + b * 65536 + wp * 256 + i0) = o;
    }
}

extern "C" void kernel_launch(void* const* d_in, const int* in_sizes, int n_in,
                              void* d_out, int out_size, void* d_ws, size_t ws_size,
                              hipStream_t stream) {
    const float* x     = (const float*)d_in[0];
    const float* W     = (const float*)d_in[1];
    const float* b_lin = (const float*)d_in[2];
    const float* a     = (const float*)d_in[3];
    const float* bias  = (const float*)d_in[4];
    float* out = (float*)d_out;

    char* ws = (char*)d_ws;
    float*          Lp  = (float*)ws;                               // 4 MB
    unsigned short* R2  = (unsigned short*)(ws + (4 << 20));        // 2 MB
    unsigned short* xT  = (unsigned short*)(ws + (6 << 20));        // 1 MB
    unsigned short* Wb  = (unsigned short*)(ws + (7 << 20));        // 0.5 MB
    float*          c2g = (float*)(ws + (7 << 20) + (512 << 10));   // 2 KB
    float*          rg  = (float*)(ws + (7 << 20) + (516 << 10));   // 8 KB

    hipMemsetAsync(rg, 0, 8 * 256 * sizeof(float), stream);
    convert_kernel<<<257, 256, 0, stream>>>(x, W, a, xT, Wb, c2g);
    mfma_gemm_kernel<<<dim3(64, 8), 256, 0, stream>>>(xT, Wb, b_lin, c2g, Lp, R2, rg);
    attn_kernel<<<512, 1024, 0, stream>>>(x, Lp, (const unsigned int*)R2, c2g, rg, bias, out);
}

// Round 6
// 116.467 us; speedup vs baseline: 1.5616x; 1.5616x over previous
//
#include <hip/hip_runtime.h>
#include <math.h>

typedef float f32x4 __attribute__((ext_vector_type(4)));
typedef __bf16 bf16x8 __attribute__((ext_vector_type(8)));
typedef unsigned short u16x8 __attribute__((ext_vector_type(8)));

__device__ __forceinline__ unsigned short f2bf(float f) {
    union { float f; unsigned int u; } v; v.f = f;
    unsigned int u = v.u;
    return (unsigned short)((u + 0x7fffu + ((u >> 16) & 1u)) >> 16);  // RNE
}
__device__ __forceinline__ float bf_lo(unsigned int d) {
    union { unsigned int u; float f; } v; v.u = d << 16; return v.f;
}
__device__ __forceinline__ float bf_hi(unsigned int d) {
    union { unsigned int u; float f; } v; v.u = d & 0xffff0000u; return v.f;
}
__device__ __forceinline__ float sigmoidf_(float v) {
    return 1.f / (1.f + __expf(-v));
}

// ---------------------------------------------------------------------------
// Kernel 1: fused convert + MFMA bf16 GEMM.  C[m][n] = sum_w A[m][w]*B[n][w].
//  left  (t<32):  A = x^T tile (staged w/ transpose+cvt), B = W[e][0:256]
//                 -> Lp[b][k][e] = C + b_lin[e]   (fp32)
//  right (t>=32): A = W[e][256:512], B = x^T tile
//                 -> R2[b][(e>>3)*2048 + j*8 + (e&7)] = bf16(C)  (8-e packs)
// 64x64 tile, 256 thr, 4 waves 2x2, each wave 32x32 via 2x2 mfma_16x16x32.
// ---------------------------------------------------------------------------
__global__ __launch_bounds__(256) void mfma_gemm_kernel(
    const float* __restrict__ x,      // (8,256,256) x[b][w][k]
    const float* __restrict__ W,      // (512,512)
    const float* __restrict__ b_lin,  // (512)
    float* __restrict__ Lp,           // (8,256,512)
    unsigned short* __restrict__ R2)  // (8, 512e x 256j packed)
{
    const int b = blockIdx.y;
    const int t = blockIdx.x;
    const bool left = (t < 32);
    int m0, n0;
    if (left) { m0 = (t >> 3) * 64; n0 = (t & 7) * 64; }
    else      { const int tt = t - 32; m0 = (tt >> 2) * 64; n0 = (tt & 3) * 64; }

    __shared__ unsigned short As[64][72];
    __shared__ unsigned short Bs[64][72];

    // staging roles: transpose-of-x tile and direct-W tile
    unsigned short (*Ts)[72] = left ? As : Bs;   // x^T tile
    unsigned short (*Ds)[72] = left ? Bs : As;   // W tile
    const int cbase = left ? m0 : n0;            // x column base (k or j)
    const int rbase = left ? n0 : m0;            // W row base (e)
    const int coff  = left ? 0 : 256;            // W column offset

    const int tid  = threadIdx.x;
    const int wv   = tid >> 6;
    const int lane = tid & 63;
    const int wy = wv >> 1, wx = wv & 1;
    const int lr = lane & 15;
    const int lk = lane >> 4;

    const float* xb = x + b * 65536;

    f32x4 acc[2][2];
    #pragma unroll
    for (int i = 0; i < 2; i++)
        #pragma unroll
        for (int jj = 0; jj < 2; jj++) acc[i][jj] = (f32x4){0.f, 0.f, 0.f, 0.f};

    const int wl = tid >> 4;         // 0..15 (w index for transpose stage)
    const int kg = tid & 15;         // 0..15 (col group)
    const int dr = tid >> 2;         // 0..63 (W row)
    const int dc = (tid & 3) * 16;   // W col group

    for (int k0 = 0; k0 < 256; k0 += 64) {
        // ---- transpose+cvt stage: Ts[c][w] = bf16(x[b][k0+w][cbase+c])
        #pragma unroll
        for (int p = 0; p < 4; p++) {
            const int w = wl + 16 * p;
            const float4 v = *(const float4*)(xb + (k0 + w) * 256 + cbase + kg * 4);
            Ts[kg * 4 + 0][w] = f2bf(v.x);
            Ts[kg * 4 + 1][w] = f2bf(v.y);
            Ts[kg * 4 + 2][w] = f2bf(v.z);
            Ts[kg * 4 + 3][w] = f2bf(v.w);
        }
        // ---- direct+cvt stage: Ds[r][c] = bf16(W[rbase+r][coff+k0+c])
        {
            const float* src = W + (rbase + dr) * 512 + coff + k0 + dc;
            const float4 v0 = *(const float4*)(src);
            const float4 v1 = *(const float4*)(src + 4);
            const float4 v2 = *(const float4*)(src + 8);
            const float4 v3 = *(const float4*)(src + 12);
            u16x8 o0, o1;
            o0[0] = f2bf(v0.x); o0[1] = f2bf(v0.y); o0[2] = f2bf(v0.z); o0[3] = f2bf(v0.w);
            o0[4] = f2bf(v1.x); o0[5] = f2bf(v1.y); o0[6] = f2bf(v1.z); o0[7] = f2bf(v1.w);
            o1[0] = f2bf(v2.x); o1[1] = f2bf(v2.y); o1[2] = f2bf(v2.z); o1[3] = f2bf(v2.w);
            o1[4] = f2bf(v3.x); o1[5] = f2bf(v3.y); o1[6] = f2bf(v3.z); o1[7] = f2bf(v3.w);
            *(u16x8*)&Ds[dr][dc]     = o0;
            *(u16x8*)&Ds[dr][dc + 8] = o1;
        }
        __syncthreads();
        #pragma unroll
        for (int kk = 0; kk < 64; kk += 32) {
            const bf16x8 a0 = *(const bf16x8*)&As[wy * 32 + lr][kk + lk * 8];
            const bf16x8 a1 = *(const bf16x8*)&As[wy * 32 + 16 + lr][kk + lk * 8];
            const bf16x8 b0 = *(const bf16x8*)&Bs[wx * 32 + lr][kk + lk * 8];
            const bf16x8 b1 = *(const bf16x8*)&Bs[wx * 32 + 16 + lr][kk + lk * 8];
            acc[0][0] = __builtin_amdgcn_mfma_f32_16x16x32_bf16(a0, b0, acc[0][0], 0, 0, 0);
            acc[0][1] = __builtin_amdgcn_mfma_f32_16x16x32_bf16(a0, b1, acc[0][1], 0, 0, 0);
            acc[1][0] = __builtin_amdgcn_mfma_f32_16x16x32_bf16(a1, b0, acc[1][0], 0, 0, 0);
            acc[1][1] = __builtin_amdgcn_mfma_f32_16x16x32_bf16(a1, b1, acc[1][1], 0, 0, 0);
        }
        __syncthreads();
    }

    // C/D layout: col = lane&15, row = (lane>>4)*4 + reg
    if (left) {
        #pragma unroll
        for (int mi = 0; mi < 2; mi++) {
            #pragma unroll
            for (int ni = 0; ni < 2; ni++) {
                const int row = m0 + wy * 32 + mi * 16 + lk * 4;   // k
                const int col = n0 + wx * 32 + ni * 16 + lr;       // e
                const float bl = b_lin[col];
                #pragma unroll
                for (int r = 0; r < 4; r++)
                    Lp[b * 131072 + (row + r) * 512 + col] = acc[mi][ni][r] + bl;
            }
        }
    } else {
        unsigned short* R2b = R2 + b * 131072;
        #pragma unroll
        for (int mi = 0; mi < 2; mi++) {
            #pragma unroll
            for (int ni = 0; ni < 2; ni++) {
                const int row = m0 + wy * 32 + mi * 16 + lk * 4;   // e base (4)
                const int col = n0 + wx * 32 + ni * 16 + lr;       // j
                ushort4 o;
                o.x = f2bf(acc[mi][ni][0]);
                o.y = f2bf(acc[mi][ni][1]);
                o.z = f2bf(acc[mi][ni][2]);
                o.w = f2bf(acc[mi][ni][3]);
                *(ushort4*)(R2b + (row >> 3) * 2048 + col * 8 + (row & 7)) = o;
            }
        }
    }
}

// ---------------------------------------------------------------------------
// Kernel 2: score + softmax + MFMA matvec + sigmoid + T-store.
// grid 256 = (i-tile of 8) x (b = blk&7, XCD-local); 1024 thr = 256 j x 4 e-q.
// score[i][j] = 0.6*(uL[i]+uR[j]) + 0.4*sum_e a[e]*|L[i,e]+R[e,j]| + bias
// ---------------------------------------------------------------------------
__global__ __launch_bounds__(1024, 4) void attn_kernel(
    const float* __restrict__ x,              // (8,256,256)
    const float* __restrict__ Lp,             // (8,256,512) fp32, b_lin folded
    const unsigned int* __restrict__ R2u,     // packed bf16 pairs
    const float* __restrict__ a,              // (512)
    const float* __restrict__ bias,           // (256,256)
    float* __restrict__ out)                  // (8,256,256)
{
    const int b   = blockIdx.x & 7;
    const int i0  = (blockIdx.x >> 3) * 8;
    const int tid = threadIdx.x;
    const int j   = tid & 255;
    const int q   = __builtin_amdgcn_readfirstlane(tid >> 8);

    __shared__ float acc2P[8192];             // [4 q][8 i][256 j]
    __shared__ float rgp[1024];               // [4 q][256 j]
    __shared__ float atf[2048];               // [8 i][256 j]
    __shared__ float u15s[8];
    __shared__ unsigned short atbf[16 * 264]; // bf16 attn, padded rows

    // ---- uL: waves 0..7, u15s[i] = 0.6 * sum_e a[e]*L[i,e]
    if (tid < 512) {
        const int i = tid >> 6, lane = tid & 63;
        const float* Lr = Lp + b * 131072 + (i0 + i) * 512 + lane * 8;
        const float* ar = a + lane * 8;
        const float4 la = *(const float4*)Lr;
        const float4 lb = *(const float4*)(Lr + 4);
        const float4 ca = *(const float4*)ar;
        const float4 cb = *(const float4*)(ar + 4);
        float p = la.x * ca.x + la.y * ca.y + la.z * ca.z + la.w * ca.w
                + lb.x * cb.x + lb.y * cb.y + lb.z * cb.z + lb.w * cb.w;
        #pragma unroll
        for (int off = 32; off; off >>= 1) p += __shfl_xor(p, off);
        if (lane == 0) u15s[i] = 0.6f * p;
    }

    // ---- score: 128 e per thread, 8 i rows; L/a via wave-uniform s_loads
    const float* Lq = Lp + b * 131072 + i0 * 512 + q * 128;  // row i: +i*512
    const float* aq = a + q * 128;
    const uint4* Rq = (const uint4*)(R2u + b * 65536) + q * 16 * 256 + j;

    float acc[8];
    #pragma unroll
    for (int i = 0; i < 8; i++) acc[i] = 0.f;
    float rsum = 0.f;

    for (int tk = 0; tk < 16; tk++) {
        const uint4 rw = Rq[tk * 256];
        float r[8];
        r[0] = bf_lo(rw.x); r[1] = bf_hi(rw.x);
        r[2] = bf_lo(rw.y); r[3] = bf_hi(rw.y);
        r[4] = bf_lo(rw.z); r[5] = bf_hi(rw.z);
        r[6] = bf_lo(rw.w); r[7] = bf_hi(rw.w);
        #pragma unroll
        for (int s = 0; s < 8; s++) {
            const int el = tk * 8 + s;
            const float ae = aq[el];
            rsum = fmaf(ae, r[s], rsum);
            #pragma unroll
            for (int i = 0; i < 8; i++) {
                const float p = Lq[i * 512 + el] + r[s];
                acc[i] = fmaf(ae, fabsf(p), acc[i]);
            }
        }
    }
    {
        float* dst = acc2P + q * 2048 + j;
        #pragma unroll
        for (int i = 0; i < 8; i++) dst[i * 256] = acc[i];
        rgp[q * 256 + j] = rsum;
    }
    __syncthreads();

    // ---- combine
    if (tid < 256) {
        const float uR = rgp[j] + rgp[256 + j] + rgp[512 + j] + rgp[768 + j];
        #pragma unroll
        for (int i = 0; i < 8; i++) {
            const float ab = acc2P[i * 256 + j] + acc2P[2048 + i * 256 + j]
                           + acc2P[4096 + i * 256 + j] + acc2P[6144 + i * 256 + j];
            atf[i * 256 + j] = u15s[i] + 0.6f * uR + 0.4f * ab
                             + bias[(i0 + i) * 256 + j];
        }
    }
    __syncthreads();

    // ---- softmax: waves 0..7, wave i -> row i; write bf16 attn
    if (tid < 512) {
        const int i = tid >> 6, lane = tid & 63;
        float v[4];
        float m = -1e30f;
        #pragma unroll
        for (int u = 0; u < 4; u++) {
            v[u] = atf[i * 256 + lane + 64 * u];
            m = fmaxf(m, v[u]);
        }
        #pragma unroll
        for (int off = 32; off; off >>= 1) m = fmaxf(m, __shfl_xor(m, off));
        float s = 0.f;
        #pragma unroll
        for (int u = 0; u < 4; u++) { v[u] = __expf(v[u] - m); s += v[u]; }
        #pragma unroll
        for (int off = 32; off; off >>= 1) s += __shfl_xor(s, off);
        const float inv = 1.f / s;
        #pragma unroll
        for (int u = 0; u < 4; u++)
            atbf[i * 264 + lane + 64 * u] = f2bf(v[u] * inv);
    }
    __syncthreads();

    // ---- matvec via MFMA: D[i][w] = sum_j attn[i][j] * x[b][w][j]
    // wave wv = n-tile (16 w); A = atbf rows (i, rows 8..15 garbage->unused)
    {
        const int nt = tid >> 6;          // 0..15
        const int lane = tid & 63;
        const int lr = lane & 15;         // w within tile / attn row
        const int lk = lane >> 4;         // k-group
        f32x4 hacc = (f32x4){0.f, 0.f, 0.f, 0.f};
        const float* xw = x + b * 65536 + (nt * 16 + lr) * 256;
        #pragma unroll
        for (int kt = 0; kt < 8; kt++) {
            const bf16x8 av = *(const bf16x8*)&atbf[lr * 264 + kt * 32 + lk * 8];
            const float4 f0 = *(const float4*)(xw + kt * 32 + lk * 8);
            const float4 f1 = *(const float4*)(xw + kt * 32 + lk * 8 + 4);
            u16x8 bu;
            bu[0] = f2bf(f0.x); bu[1] = f2bf(f0.y); bu[2] = f2bf(f0.z); bu[3] = f2bf(f0.w);
            bu[4] = f2bf(f1.x); bu[5] = f2bf(f1.y); bu[6] = f2bf(f1.z); bu[7] = f2bf(f1.w);
            const bf16x8 bv = *(const bf16x8*)&bu;
            hacc = __builtin_amdgcn_mfma_f32_16x16x32_bf16(av, bv, hacc, 0, 0, 0);
        }
        // D: col(lane&15)=w, row(lk*4+r)=i; valid i rows 0..7 -> lk<2
        if (lk < 2) {
            float4 o;
            o.x = sigmoidf_(hacc[0]);
            o.y = sigmoidf_(hacc[1]);
            o.z = sigmoidf_(hacc[2]);
            o.w = sigmoidf_(hacc[3]);
            *(float4*)(out + b * 65536 + (nt * 16 + lr) * 256 + i0 + lk * 4) = o;
        }
    }
}

extern "C" void kernel_launch(void* const* d_in, const int* in_sizes, int n_in,
                              void* d_out, int out_size, void* d_ws, size_t ws_size,
                              hipStream_t stream) {
    const float* x     = (const float*)d_in[0];
    const float* W     = (const float*)d_in[1];
    const float* b_lin = (const float*)d_in[2];
    const float* a     = (const float*)d_in[3];
    const float* bias  = (const float*)d_in[4];
    float* out = (float*)d_out;

    char* ws = (char*)d_ws;
    float*          Lp = (float*)ws;                          // 4 MB
    unsigned short* R2 = (unsigned short*)(ws + (4 << 20));   // 2 MB

    mfma_gemm_kernel<<<dim3(64, 8), 256, 0, stream>>>(x, W, b_lin, Lp, R2);
    attn_kernel<<<256, 1024, 0, stream>>>(x, Lp, (const unsigned int*)R2, a, bias, out);
}